// Round 2
// baseline (295.556 us; speedup 1.0000x reference)
//
#include <hip/hip_runtime.h>

#define NB 4
#define NC 128
#define NH 184
#define NW 320
#define TW 64          // output w-tile per block
#define NJ 80          // staged f2 columns per row: [w0-4, w0+76)
#define ND 9           // displacements per axis

typedef __attribute__((ext_vector_type(8))) short bf16x8;
typedef __attribute__((ext_vector_type(4))) float f32x4;

__global__ __launch_bounds__(256) void corr_mfma(const float* __restrict__ f1,
                                                 const float* __restrict__ f2,
                                                 float* __restrict__ out) {
  const int wt = blockIdx.x;      // 0..4
  const int h  = blockIdx.y;      // 0..183
  const int b  = blockIdx.z;      // 0..3
  const int w0 = wt * TW;
  const int t  = threadIdx.x;     // 0..255
  const int lane = t & 63;
  const int wave = t >> 6;        // M-subtile owner

  // [row][c] bf16, XOR-swizzled in 8-short units: idx ^= (row&7)<<3
  __shared__ __align__(16) unsigned short a_s[TW * NC];  // f1 tile
  __shared__ __align__(16) unsigned short b_s[NJ * NC];  // f2 row window
  __shared__ float scr[NJ][17];       // sumsq partials (padded)
  __shared__ float invn1_s[TW];
  __shared__ float invn2_s[NJ];
  __shared__ float out_s[ND][TW];     // one dy-slab of outputs

  const size_t HW = (size_t)NH * NW;

  // ---------------- stage A: f1[b, :, h, w0..w0+63] ----------------
  {
    const int w  = t & 63;
    const int cg = t >> 6;            // 0..3 -> channels [cg*32, cg*32+32)
    float ss = 0.f;
    #pragma unroll
    for (int cc = 0; cc < 4; ++cc) {
      const int cb = cg * 32 + cc * 8;
      const float* p = f1 + ((size_t)b * NC + cb) * HW + (size_t)h * NW + w0 + w;
      float v[8];
      #pragma unroll
      for (int i = 0; i < 8; ++i) v[i] = p[i * HW];   // lane-coalesced per c
      bf16x8 sv;
      #pragma unroll
      for (int i = 0; i < 8; ++i) {
        unsigned int u = __float_as_uint(v[i]);
        u = (u + 0x7fffu + ((u >> 16) & 1u)) & 0xffff0000u;  // RNE to bf16
        float vb = __uint_as_float(u);
        ss += vb * vb;                                       // norm of the bf16 vector
        sv[i] = (short)(u >> 16);
      }
      const int idx = (w * NC + cb) ^ ((w & 7) << 3);
      *reinterpret_cast<bf16x8*>(&a_s[idx]) = sv;     // ds_write_b128
    }
    scr[w][cg] = ss;
  }
  __syncthreads();
  if (t < TW) {
    float s = scr[t][0] + scr[t][1] + scr[t][2] + scr[t][3];
    invn1_s[t] = 1.f / fmaxf(sqrtf(s), 1e-12f);
  }

  for (int dyi = 0; dyi < ND; ++dyi) {
    __syncthreads();                       // b_s / scr / out_s safe to reuse
    const int hr = h + 4 - dyi;            // h - dy  (reference: f2[h-dy, w-dx])
    // ---------------- stage B: f2[b, :, hr, w0-4 .. w0+75] ----------------
    {
      const int jl16 = t & 15;
      const int cg   = t >> 4;             // 0..15 -> channels [cg*8, cg*8+8)
      const int cb   = cg * 8;
      const bool rowok = (hr >= 0) && (hr < NH);
      #pragma unroll
      for (int s5 = 0; s5 < 5; ++s5) {
        const int jl = s5 * 16 + jl16;     // local j 0..79
        const int jg = w0 - 4 + jl;        // global j
        float v[8];
        if (rowok && jg >= 0 && jg < NW) {
          const float* p = f2 + ((size_t)b * NC + cb) * HW + (size_t)hr * NW + jg;
          #pragma unroll
          for (int i = 0; i < 8; ++i) v[i] = p[i * HW];
        } else {
          #pragma unroll
          for (int i = 0; i < 8; ++i) v[i] = 0.f;     // zero-pad boundary
        }
        float ss = 0.f;
        bf16x8 sv;
        #pragma unroll
        for (int i = 0; i < 8; ++i) {
          unsigned int u = __float_as_uint(v[i]);
          u = (u + 0x7fffu + ((u >> 16) & 1u)) & 0xffff0000u;
          float vb = __uint_as_float(u);
          ss += vb * vb;
          sv[i] = (short)(u >> 16);
        }
        const int idx = (jl * NC + cb) ^ ((jl & 7) << 3);
        *reinterpret_cast<bf16x8*>(&b_s[idx]) = sv;
        scr[jl][cg] = ss;
      }
    }
    __syncthreads();
    if (t < NJ) {
      float s = 0.f;
      #pragma unroll
      for (int i = 0; i < 16; ++i) s += scr[t][i];
      invn2_s[t] = 1.f / fmaxf(sqrtf(s), 1e-12f);
    }
    __syncthreads();
    // ---------------- MFMA: wave m computes w in [16m,16m+16), 2 N-tiles ----------------
    {
      const int m = wave;
      const int q = lane >> 4;
      const int n = lane & 15;
      f32x4 acc0 = {0.f, 0.f, 0.f, 0.f};
      f32x4 acc1 = {0.f, 0.f, 0.f, 0.f};
      const int wl  = m * 16 + n;          // A row (m-index)
      const int jl0 = m * 16 + n;          // B col, N-tile 0
      const int jl1 = m * 16 + 16 + n;     // B col, N-tile 1
      #pragma unroll
      for (int kk = 0; kk < 4; ++kk) {
        const int c0 = kk * 32 + q * 8;    // k-fragment: 8 contiguous c per lane
        bf16x8 av  = *reinterpret_cast<const bf16x8*>(&a_s[(wl  * NC + c0) ^ ((wl  & 7) << 3)]);
        bf16x8 bv0 = *reinterpret_cast<const bf16x8*>(&b_s[(jl0 * NC + c0) ^ ((jl0 & 7) << 3)]);
        bf16x8 bv1 = *reinterpret_cast<const bf16x8*>(&b_s[(jl1 * NC + c0) ^ ((jl1 & 7) << 3)]);
        acc0 = __builtin_amdgcn_mfma_f32_16x16x32_bf16(av, bv0, acc0, 0, 0, 0);
        acc1 = __builtin_amdgcn_mfma_f32_16x16x32_bf16(av, bv1, acc1, 0, 0, 0);
      }
      // D elem (reg r, lane): row=q*4+r -> w, col=n -> j.  dx = w - j, keep |dx|<=4
      #pragma unroll
      for (int T = 0; T < 2; ++T) {
        const f32x4 a = T ? acc1 : acc0;
        const int jl = m * 16 + T * 16 + n;
        const float i2 = invn2_s[jl];
        #pragma unroll
        for (int r = 0; r < 4; ++r) {
          const int wr = m * 16 + q * 4 + r;
          const int dx = wr + 4 - jl;      // w - j  (reference: f2[w-dx] at col j)
          if (dx >= -4 && dx <= 4) {
            out_s[dx + 4][wr] = a[r] * invn1_s[wr] * i2;
          }
        }
      }
    }
    __syncthreads();
    // ---------------- coalesced global write of this dy-slab ----------------
    #pragma unroll
    for (int kidx = 0; kidx < 3; ++kidx) {
      const int k = kidx * 256 + t;
      if (k < ND * TW) {
        const int dx = k >> 6;
        const int wl = k & 63;
        const int d  = dyi * ND + dx;      // d = (dy+4)*9 + (dx+4), reference order
        out[(((size_t)b * 81 + d) * NH + h) * NW + w0 + wl] = out_s[dx][wl];
      }
    }
  }
}

extern "C" void kernel_launch(void* const* d_in, const int* in_sizes, int n_in,
                              void* d_out, int out_size, void* d_ws, size_t ws_size,
                              hipStream_t stream) {
  const float* f1 = (const float*)d_in[0];
  const float* f2 = (const float*)d_in[1];
  float* out = (float*)d_out;
  dim3 grid(NW / TW, NH, NB);   // 5 x 184 x 4 = 3680 blocks
  corr_mfma<<<grid, 256, 0, stream>>>(f1, f2, out);
}

// Round 3
// 207.582 us; speedup vs baseline: 1.4238x; 1.4238x over previous
//
#include <hip/hip_runtime.h>

#define NB 4
#define NC 128
#define NH 184
#define NW 320
#define TW 64
#define NJ 80
#define ND 9
#define NPIX (NB * NH * NW)                       // 235520 pixels per tensor
#define WS_NEEDED ((size_t)2 * NPIX * NC * 2)     // 120.6 MB of bf16

typedef __attribute__((ext_vector_type(8))) short bf16x8;
typedef __attribute__((ext_vector_type(4))) float f32x4;

__device__ __forceinline__ unsigned short f2bf(float f) {
  unsigned int u = __float_as_uint(f);
  u = u + 0x7fffu + ((u >> 16) & 1u);             // RNE
  return (unsigned short)(u >> 16);
}

// ================= K1: normalize + CHW->HWC transpose + fp32->bf16 =================
__global__ __launch_bounds__(256) void normalize_hwc(const float* __restrict__ f1,
                                                     const float* __restrict__ f2,
                                                     unsigned short* __restrict__ fn) {
  const int wseg = blockIdx.x;            // 0..4
  const int h    = blockIdx.y;            // 0..183
  const int bz   = blockIdx.z;            // 0..7 = tensor*4 + b
  const int b    = bz & 3;
  const float* src = (bz < 4) ? f1 : f2;
  unsigned short* dst = fn + ((bz < 4) ? (size_t)0 : (size_t)NPIX * NC);

  const int t  = threadIdx.x;
  const int w  = t & 63;                  // pixel within segment
  const int cg = t >> 6;                  // channel group: [cg*32, cg*32+32)
  const size_t HW = (size_t)NH * NW;

  __shared__ float scr[64][5];            // pad-5: conflict-free
  __shared__ float invn_s[64];

  float v[32];
  float ss = 0.f;
  const float* p = src + ((size_t)b * NC + cg * 32) * HW + (size_t)h * NW + wseg * 64 + w;
  #pragma unroll
  for (int i = 0; i < 32; ++i) {          // 64-lane-coalesced per channel
    v[i] = p[i * HW];
    ss += v[i] * v[i];
  }
  scr[w][cg] = ss;
  __syncthreads();
  if (t < 64) {
    float s = scr[t][0] + scr[t][1] + scr[t][2] + scr[t][3];
    invn_s[t] = 1.f / fmaxf(sqrtf(s), 1e-12f);
  }
  __syncthreads();
  const float inv = invn_s[w];
  unsigned short* d = dst + ((size_t)(b * NH + h) * NW + wseg * 64 + w) * NC + cg * 32;
  #pragma unroll
  for (int cc = 0; cc < 4; ++cc) {
    bf16x8 sv;
    #pragma unroll
    for (int i = 0; i < 8; ++i) sv[i] = (short)f2bf(v[cc * 8 + i] * inv);
    *reinterpret_cast<bf16x8*>(d + cc * 8) = sv;  // 16B store
  }
}

// ================= K2: banded MFMA correlation, registers-only operands =================
__global__ __launch_bounds__(256) void corr_hwc(const unsigned short* __restrict__ fn,
                                                float* __restrict__ out) {
  // bijective XCD swizzle: 3680 = 8 * 460 -> each XCD gets a contiguous h-run
  const int bid = blockIdx.x;
  const int swz = (bid & 7) * 460 + (bid >> 3);
  const int wt = swz % 5;
  const int h  = (swz / 5) % NH;
  const int b  = swz / (5 * NH);
  const int w0 = wt * TW;

  const int t = threadIdx.x;
  const int lane = t & 63;
  const int wave = t >> 6;                // owns w in [wave*16, wave*16+16)
  const int q = lane >> 4;
  const int n = lane & 15;

  const unsigned short* f1n = fn;
  const unsigned short* f2n = fn + (size_t)NPIX * NC;

  __shared__ float out_s[27][65];         // 3 dy-slabs x 9 dx x 64 w, pad-65

  // A fragments: loaded once, reused for all 81 displacements
  const unsigned short* arow = f1n + ((size_t)(b * NH + h) * NW + w0 + wave * 16 + n) * NC;
  bf16x8 av[4];
  #pragma unroll
  for (int kk = 0; kk < 4; ++kk)
    av[kk] = *reinterpret_cast<const bf16x8*>(arow + kk * 32 + q * 8);

  const int jb0 = w0 + wave * 16 - 4 + n;       // B cols, N-tile 0
  const int jb1 = w0 + wave * 16 + 12 + n;      // B cols, N-tile 1

  #pragma unroll
  for (int chunk = 0; chunk < 3; ++chunk) {
    f32x4 acc[3][2];
    #pragma unroll
    for (int dd = 0; dd < 3; ++dd)
      #pragma unroll
      for (int T = 0; T < 2; ++T)
        acc[dd][T] = (f32x4){0.f, 0.f, 0.f, 0.f};

    #pragma unroll
    for (int dd = 0; dd < 3; ++dd) {
      const int dyi = chunk * 3 + dd;
      const int hr = h + 4 - dyi;               // h - dy (ref: f2[h-dy, w-dx])
      if (hr >= 0 && hr < NH) {                 // OOB row -> acc stays 0 (zero-pad)
        const unsigned short* brow = f2n + (size_t)(b * NH + hr) * NW * NC;
        #pragma unroll
        for (int T = 0; T < 2; ++T) {
          const int j = T ? jb1 : jb0;
          bf16x8 bv[4];
          if (j >= 0 && j < NW) {
            const unsigned short* bp = brow + (size_t)j * NC;
            #pragma unroll
            for (int kk = 0; kk < 4; ++kk)
              bv[kk] = *reinterpret_cast<const bf16x8*>(bp + kk * 32 + q * 8);
          } else {
            #pragma unroll
            for (int kk = 0; kk < 4; ++kk)
              #pragma unroll
              for (int e = 0; e < 8; ++e) bv[kk][e] = 0;
          }
          #pragma unroll
          for (int kk = 0; kk < 4; ++kk)
            acc[dd][T] = __builtin_amdgcn_mfma_f32_16x16x32_bf16(av[kk], bv[kk], acc[dd][T], 0, 0, 0);
        }
      }
    }

    __syncthreads();                            // out_s readers of prev chunk done
    // D elem (reg r): w-local = wave*16+q*4+r, col j offset from n; dx = w - j
    #pragma unroll
    for (int dd = 0; dd < 3; ++dd)
      #pragma unroll
      for (int T = 0; T < 2; ++T)
        #pragma unroll
        for (int r = 0; r < 4; ++r) {
          const int wl = wave * 16 + q * 4 + r;
          const int dx = q * 4 + r + 4 - T * 16 - n;
          if (dx >= -4 && dx <= 4)
            out_s[dd * 9 + dx + 4][wl] = acc[dd][T][r];
        }
    __syncthreads();
    #pragma unroll
    for (int kidx = 0; kidx < 7; ++kidx) {
      const int k = kidx * 256 + t;
      if (k < 27 * 64) {
        const int dl = k >> 6;                  // local d within chunk
        const int wl = k & 63;
        out[(((size_t)b * 81 + chunk * 27 + dl) * NH + h) * NW + w0 + wl] = out_s[dl][wl];
      }
    }
  }
}

// ================= fallback: round-2 fused kernel (used if ws too small) =================
__global__ __launch_bounds__(256) void corr_mfma(const float* __restrict__ f1,
                                                 const float* __restrict__ f2,
                                                 float* __restrict__ out) {
  const int wt = blockIdx.x;
  const int h  = blockIdx.y;
  const int b  = blockIdx.z;
  const int w0 = wt * TW;
  const int t  = threadIdx.x;
  const int lane = t & 63;
  const int wave = t >> 6;

  __shared__ __align__(16) unsigned short a_s[TW * NC];
  __shared__ __align__(16) unsigned short b_s[NJ * NC];
  __shared__ float scr[NJ][17];
  __shared__ float invn1_s[TW];
  __shared__ float invn2_s[NJ];
  __shared__ float out_s[ND][TW];

  const size_t HW = (size_t)NH * NW;

  {
    const int w  = t & 63;
    const int cg = t >> 6;
    float ss = 0.f;
    #pragma unroll
    for (int cc = 0; cc < 4; ++cc) {
      const int cb = cg * 32 + cc * 8;
      const float* p = f1 + ((size_t)b * NC + cb) * HW + (size_t)h * NW + w0 + w;
      float v[8];
      #pragma unroll
      for (int i = 0; i < 8; ++i) v[i] = p[i * HW];
      bf16x8 sv;
      #pragma unroll
      for (int i = 0; i < 8; ++i) {
        unsigned int u = __float_as_uint(v[i]);
        u = (u + 0x7fffu + ((u >> 16) & 1u)) & 0xffff0000u;
        float vb = __uint_as_float(u);
        ss += vb * vb;
        sv[i] = (short)(u >> 16);
      }
      const int idx = (w * NC + cb) ^ ((w & 7) << 3);
      *reinterpret_cast<bf16x8*>(&a_s[idx]) = sv;
    }
    scr[w][cg] = ss;
  }
  __syncthreads();
  if (t < TW) {
    float s = scr[t][0] + scr[t][1] + scr[t][2] + scr[t][3];
    invn1_s[t] = 1.f / fmaxf(sqrtf(s), 1e-12f);
  }

  for (int dyi = 0; dyi < ND; ++dyi) {
    __syncthreads();
    const int hr = h + 4 - dyi;
    {
      const int jl16 = t & 15;
      const int cg   = t >> 4;
      const int cb   = cg * 8;
      const bool rowok = (hr >= 0) && (hr < NH);
      #pragma unroll
      for (int s5 = 0; s5 < 5; ++s5) {
        const int jl = s5 * 16 + jl16;
        const int jg = w0 - 4 + jl;
        float v[8];
        if (rowok && jg >= 0 && jg < NW) {
          const float* p = f2 + ((size_t)b * NC + cb) * HW + (size_t)hr * NW + jg;
          #pragma unroll
          for (int i = 0; i < 8; ++i) v[i] = p[i * HW];
        } else {
          #pragma unroll
          for (int i = 0; i < 8; ++i) v[i] = 0.f;
        }
        float ss = 0.f;
        bf16x8 sv;
        #pragma unroll
        for (int i = 0; i < 8; ++i) {
          unsigned int u = __float_as_uint(v[i]);
          u = (u + 0x7fffu + ((u >> 16) & 1u)) & 0xffff0000u;
          float vb = __uint_as_float(u);
          ss += vb * vb;
          sv[i] = (short)(u >> 16);
        }
        const int idx = (jl * NC + cb) ^ ((jl & 7) << 3);
        *reinterpret_cast<bf16x8*>(&b_s[idx]) = sv;
        scr[jl][cg] = ss;
      }
    }
    __syncthreads();
    if (t < NJ) {
      float s = 0.f;
      #pragma unroll
      for (int i = 0; i < 16; ++i) s += scr[t][i];
      invn2_s[t] = 1.f / fmaxf(sqrtf(s), 1e-12f);
    }
    __syncthreads();
    {
      const int m = wave;
      const int q = lane >> 4;
      const int n = lane & 15;
      f32x4 acc0 = {0.f, 0.f, 0.f, 0.f};
      f32x4 acc1 = {0.f, 0.f, 0.f, 0.f};
      const int wl  = m * 16 + n;
      const int jl0 = m * 16 + n;
      const int jl1 = m * 16 + 16 + n;
      #pragma unroll
      for (int kk = 0; kk < 4; ++kk) {
        const int c0 = kk * 32 + q * 8;
        bf16x8 av  = *reinterpret_cast<const bf16x8*>(&a_s[(wl  * NC + c0) ^ ((wl  & 7) << 3)]);
        bf16x8 bv0 = *reinterpret_cast<const bf16x8*>(&b_s[(jl0 * NC + c0) ^ ((jl0 & 7) << 3)]);
        bf16x8 bv1 = *reinterpret_cast<const bf16x8*>(&b_s[(jl1 * NC + c0) ^ ((jl1 & 7) << 3)]);
        acc0 = __builtin_amdgcn_mfma_f32_16x16x32_bf16(av, bv0, acc0, 0, 0, 0);
        acc1 = __builtin_amdgcn_mfma_f32_16x16x32_bf16(av, bv1, acc1, 0, 0, 0);
      }
      #pragma unroll
      for (int T = 0; T < 2; ++T) {
        const f32x4 a = T ? acc1 : acc0;
        const int jl = m * 16 + T * 16 + n;
        const float i2 = invn2_s[jl];
        #pragma unroll
        for (int r = 0; r < 4; ++r) {
          const int wr = m * 16 + q * 4 + r;
          const int dx = wr + 4 - jl;
          if (dx >= -4 && dx <= 4) {
            out_s[dx + 4][wr] = a[r] * invn1_s[wr] * i2;
          }
        }
      }
    }
    __syncthreads();
    #pragma unroll
    for (int kidx = 0; kidx < 3; ++kidx) {
      const int k = kidx * 256 + t;
      if (k < ND * TW) {
        const int dx = k >> 6;
        const int wl = k & 63;
        const int d  = dyi * ND + dx;
        out[(((size_t)b * 81 + d) * NH + h) * NW + w0 + wl] = out_s[dx][wl];
      }
    }
  }
}

extern "C" void kernel_launch(void* const* d_in, const int* in_sizes, int n_in,
                              void* d_out, int out_size, void* d_ws, size_t ws_size,
                              hipStream_t stream) {
  const float* f1 = (const float*)d_in[0];
  const float* f2 = (const float*)d_in[1];
  float* out = (float*)d_out;
  if (d_ws != nullptr && ws_size >= WS_NEEDED) {
    unsigned short* fn = (unsigned short*)d_ws;
    normalize_hwc<<<dim3(NW / TW, NH, 8), 256, 0, stream>>>(f1, f2, fn);
    corr_hwc<<<dim3(NW / TW * NH * NB), 256, 0, stream>>>(fn, out);
  } else {
    corr_mfma<<<dim3(NW / TW, NH, NB), 256, 0, stream>>>(f1, f2, out);
  }
}